// Round 1
// baseline (1804.767 us; speedup 1.0000x reference)
//
#include <hip/hip_runtime.h>

#define NPTS 8192
#define NB 4
#define NCH 128
#define NQK 32
#define TM 64

// ---------------------------------------------------------------------------
// xhat: normalized xyz * sqrt(0.1), padded to 4 -> QX[b][n][4]
// ---------------------------------------------------------------------------
__global__ void xhat_kernel(const float* __restrict__ xyz, float* __restrict__ QX) {
  int i = blockIdx.x * 256 + threadIdx.x;  // i = b*NPTS + n
  float a = xyz[(size_t)i * 3 + 0];
  float b = xyz[(size_t)i * 3 + 1];
  float c = xyz[(size_t)i * 3 + 2];
  float r = sqrtf(a * a + b * b + c * c) + 1e-8f;
  float s = 0.31622776601683794f / r;  // sqrt(0.1)
  float4 o;
  o.x = a * s; o.y = b * s; o.z = c * s; o.w = 0.f;
  *(float4*)(QX + (size_t)i * 4) = o;
}

// ---------------------------------------------------------------------------
// Projections: z=0 -> q (QP[b][n][32]), z=1 -> k (KP[b][n][32]),
// z=2..5 -> v rows (z-2)*32..+31 into VP[b][n][128]
// ---------------------------------------------------------------------------
__global__ __launch_bounds__(256, 4)
void proj_kernel(const float* __restrict__ x,
                 const float* __restrict__ Wq, const float* __restrict__ bq,
                 const float* __restrict__ Wk, const float* __restrict__ bk,
                 const float* __restrict__ Wv, const float* __restrict__ bv,
                 float* __restrict__ QP, float* __restrict__ KP,
                 float* __restrict__ VP) {
  __shared__ float wt[128 * 36];     // W^T slice: wt[c*36 + r], r<32
  __shared__ float stage[256 * 33];  // padded transpose staging
  const int tid = threadIdx.x;
  const int b = blockIdx.y, z = blockIdx.z;
  const int n0 = blockIdx.x * 256;

  const float* W; const float* bias; float* dst; int dstride, c0;
  if (z == 0)      { W = Wq; bias = bq; dst = QP; dstride = 32;  c0 = 0; }
  else if (z == 1) { W = Wk; bias = bk; dst = KP; dstride = 32;  c0 = 0; }
  else { c0 = (z - 2) * 32; W = Wv + (size_t)c0 * 128; bias = bv + c0;
         dst = VP; dstride = 128; }

  for (int idx = tid; idx < 32 * 128; idx += 256) {
    int r = idx >> 7, c = idx & 127;
    wt[c * 36 + r] = W[idx];
  }
  __syncthreads();

  const int n = n0 + tid;
  float acc[32];
#pragma unroll
  for (int j = 0; j < 32; ++j) acc[j] = bias[j];

  const float* xb = x + (size_t)b * NCH * NPTS + n;
#pragma unroll 4
  for (int c = 0; c < 128; ++c) {
    float xv = xb[(size_t)c * NPTS];
    const float4* w4 = (const float4*)&wt[c * 36];
#pragma unroll
    for (int j4 = 0; j4 < 8; ++j4) {
      float4 w = w4[j4];
      acc[j4 * 4 + 0] = fmaf(w.x, xv, acc[j4 * 4 + 0]);
      acc[j4 * 4 + 1] = fmaf(w.y, xv, acc[j4 * 4 + 1]);
      acc[j4 * 4 + 2] = fmaf(w.z, xv, acc[j4 * 4 + 2]);
      acc[j4 * 4 + 3] = fmaf(w.w, xv, acc[j4 * 4 + 3]);
    }
  }

#pragma unroll
  for (int j = 0; j < 32; ++j) stage[tid * 33 + j] = acc[j];
  __syncthreads();

  const int c4 = tid & 7, nsub = tid >> 3;
  for (int pass = 0; pass < 8; ++pass) {
    int ni = nsub + pass * 32;
    float4 v;
    v.x = stage[ni * 33 + c4 * 4 + 0];
    v.y = stage[ni * 33 + c4 * 4 + 1];
    v.z = stage[ni * 33 + c4 * 4 + 2];
    v.w = stage[ni * 33 + c4 * 4 + 3];
    *(float4*)&dst[((size_t)b * NPTS + n0 + ni) * dstride + c0 + c4 * 4] = v;
  }
}

// ---------------------------------------------------------------------------
// Flash attention, online softmax. lane = query, acc[128] in regs.
// m-split over blockIdx.z. FUSED: S==1, write final out directly.
// ---------------------------------------------------------------------------
template <bool FUSED>
__global__ __launch_bounds__(256, 2)
void attn_kernel(const float* __restrict__ QP, const float* __restrict__ KP,
                 const float* __restrict__ QX, const float* __restrict__ VP,
                 float* __restrict__ PACC, float* __restrict__ PM,
                 float* __restrict__ PL,
                 const float* __restrict__ x, const float* __restrict__ gamma,
                 float* __restrict__ out, int msteps) {
  __shared__ float kx[TM * 36];    // k(32) + xhat(4) per m
  __shared__ float vv[TM * 128];   // v per m
  const int tid = threadIdx.x;
  const int b = blockIdx.y, s = blockIdx.z;
  const int n = blockIdx.x * 256 + tid;

  float q[32], qx[4];
  {
    const float4* q4 = (const float4*)(QP + ((size_t)b * NPTS + n) * 32);
#pragma unroll
    for (int i = 0; i < 8; ++i) {
      float4 t = q4[i];
      q[i * 4 + 0] = t.x; q[i * 4 + 1] = t.y; q[i * 4 + 2] = t.z; q[i * 4 + 3] = t.w;
    }
    float4 t = *(const float4*)(QX + ((size_t)b * NPTS + n) * 4);
    qx[0] = t.x; qx[1] = t.y; qx[2] = t.z; qx[3] = t.w;
  }

  float acc[128];
#pragma unroll
  for (int c = 0; c < 128; ++c) acc[c] = 0.f;
  float M = 0.f, l = 0.f;  // M=0 is safe (scores bounded ~±30; exp stays finite)

  const int m0 = s * msteps;
  for (int mt = 0; mt < msteps; mt += TM) {
    __syncthreads();
    const int mbase = m0 + mt;
    for (int idx = tid; idx < TM * 9; idx += 256) {
      int ml = idx / 9, f4 = idx % 9;
      float4 t;
      if (f4 < 8)
        t = *(const float4*)(KP + ((size_t)b * NPTS + mbase + ml) * 32 + f4 * 4);
      else
        t = *(const float4*)(QX + ((size_t)b * NPTS + mbase + ml) * 4);
      *(float4*)&kx[ml * 36 + f4 * 4] = t;
    }
    for (int idx = tid; idx < TM * 32; idx += 256) {
      int ml = idx >> 5, c4 = idx & 31;
      *(float4*)&vv[ml * 128 + c4 * 4] =
          *(const float4*)(VP + ((size_t)b * NPTS + mbase + ml) * 128 + c4 * 4);
    }
    __syncthreads();

    for (int ml = 0; ml < TM; ++ml) {
      const float4* kr4 = (const float4*)&kx[ml * 36];
      float s0 = 0.f, s1 = 0.f, s2 = 0.f, s3 = 0.f;
#pragma unroll
      for (int i4 = 0; i4 < 8; ++i4) {
        float4 kf = kr4[i4];
        s0 = fmaf(q[i4 * 4 + 0], kf.x, s0);
        s1 = fmaf(q[i4 * 4 + 1], kf.y, s1);
        s2 = fmaf(q[i4 * 4 + 2], kf.z, s2);
        s3 = fmaf(q[i4 * 4 + 3], kf.w, s3);
      }
      {
        float4 kf = kr4[8];
        s0 = fmaf(qx[0], kf.x, s0);
        s1 = fmaf(qx[1], kf.y, s1);
        s2 = fmaf(qx[2], kf.z, s2);
      }
      float ss = (s0 + s1) + (s2 + s3);

      float p;
      if (ss > M) {
        float alpha = __expf(M - ss);
        M = ss;
        l *= alpha;
#pragma unroll
        for (int c = 0; c < 128; ++c) acc[c] *= alpha;
        p = 1.f;
      } else {
        p = __expf(ss - M);
      }
      l += p;

      const float4* vr4 = (const float4*)&vv[ml * 128];
#pragma unroll
      for (int c4 = 0; c4 < 32; ++c4) {
        float4 vf = vr4[c4];
        acc[c4 * 4 + 0] = fmaf(p, vf.x, acc[c4 * 4 + 0]);
        acc[c4 * 4 + 1] = fmaf(p, vf.y, acc[c4 * 4 + 1]);
        acc[c4 * 4 + 2] = fmaf(p, vf.z, acc[c4 * 4 + 2]);
        acc[c4 * 4 + 3] = fmaf(p, vf.w, acc[c4 * 4 + 3]);
      }
    }
  }

  if (FUSED) {
    float inv = gamma[0] / l;
    const float* xb = x + (size_t)b * NCH * NPTS + n;
    float* ob = out + (size_t)b * NCH * NPTS + n;
#pragma unroll
    for (int c = 0; c < 128; ++c)
      ob[(size_t)c * NPTS] = fmaf(acc[c], inv, xb[(size_t)c * NPTS]);
  } else {
    size_t sb = (size_t)s * NB + b;
    PM[sb * NPTS + n] = M;
    PL[sb * NPTS + n] = l;
#pragma unroll
    for (int c = 0; c < 128; ++c)
      PACC[(sb * 128 + c) * NPTS + n] = acc[c];
  }
}

// ---------------------------------------------------------------------------
// Merge 4 m-split partials + residual + gamma
// ---------------------------------------------------------------------------
__global__ void merge_kernel(const float* __restrict__ PACC,
                             const float* __restrict__ PM,
                             const float* __restrict__ PL,
                             const float* __restrict__ x,
                             const float* __restrict__ gamma,
                             float* __restrict__ out) {
  const int tid = threadIdx.x;
  const int b = blockIdx.y;
  const int n = blockIdx.x * 256 + tid;

  float m[4], w[4];
  float M = -1e30f;
#pragma unroll
  for (int s = 0; s < 4; ++s) {
    m[s] = PM[((size_t)s * NB + b) * NPTS + n];
    M = fmaxf(M, m[s]);
  }
  float L = 0.f;
#pragma unroll
  for (int s = 0; s < 4; ++s) {
    w[s] = __expf(m[s] - M);
    L += w[s] * PL[((size_t)s * NB + b) * NPTS + n];
  }
  float g = gamma[0] / L;
#pragma unroll
  for (int s = 0; s < 4; ++s) w[s] *= g;

  const float* xb = x + (size_t)b * NCH * NPTS + n;
  float* ob = out + (size_t)b * NCH * NPTS + n;
  for (int c = 0; c < 128; ++c) {
    float a = 0.f;
#pragma unroll
    for (int s = 0; s < 4; ++s)
      a = fmaf(w[s], PACC[(((size_t)s * NB + b) * 128 + c) * NPTS + n], a);
    ob[(size_t)c * NPTS] = a + xb[(size_t)c * NPTS];
  }
}

// ---------------------------------------------------------------------------
extern "C" void kernel_launch(void* const* d_in, const int* in_sizes, int n_in,
                              void* d_out, int out_size, void* d_ws,
                              size_t ws_size, hipStream_t stream) {
  const float* x     = (const float*)d_in[0];
  const float* xyz   = (const float*)d_in[1];
  const float* Wq    = (const float*)d_in[2];
  const float* bq    = (const float*)d_in[3];
  const float* Wk    = (const float*)d_in[4];
  const float* bk    = (const float*)d_in[5];
  const float* Wv    = (const float*)d_in[6];
  const float* bv    = (const float*)d_in[7];
  const float* gamma = (const float*)d_in[8];
  float* out = (float*)d_out;
  float* ws  = (float*)d_ws;

  const size_t BN = (size_t)NB * NPTS;
  size_t o = 0;
  float* QP = ws + o; o += BN * 32;
  float* KP = ws + o; o += BN * 32;
  float* QX = ws + o; o += BN * 4;
  float* VP = ws + o; o += BN * 128;
  size_t base_floats = o;
  // partials for S=4
  float* PM = ws + o;   o += 4 * BN;
  float* PL = ws + o;   o += 4 * BN;
  float* PACC = ws + o; o += 4 * BN * 128;
  const size_t need4 = o * sizeof(float);
  const int S = (ws_size >= need4) ? 4 : 1;

  xhat_kernel<<<(NB * NPTS) / 256, 256, 0, stream>>>(xyz, QX);
  proj_kernel<<<dim3(NPTS / 256, NB, 6), 256, 0, stream>>>(
      x, Wq, bq, Wk, bk, Wv, bv, QP, KP, VP);

  if (S == 4) {
    attn_kernel<false><<<dim3(NPTS / 256, NB, 4), 256, 0, stream>>>(
        QP, KP, QX, VP, PACC, PM, PL, x, gamma, out, NPTS / 4);
    merge_kernel<<<dim3(NPTS / 256, NB), 256, 0, stream>>>(PACC, PM, PL, x,
                                                           gamma, out);
  } else {
    attn_kernel<true><<<dim3(NPTS / 256, NB, 1), 256, 0, stream>>>(
        QP, KP, QX, VP, nullptr, nullptr, nullptr, x, gamma, out, NPTS);
  }
  (void)in_sizes; (void)n_in; (void)out_size; (void)base_floats;
}

// Round 2
// 327.928 us; speedup vs baseline: 5.5035x; 5.5035x over previous
//
#include <hip/hip_runtime.h>

#define NPTS 8192
#define NB 4
#define NCH 128

typedef unsigned short ushort_t;
typedef unsigned int uint_t;
typedef __attribute__((ext_vector_type(8))) short bf16x8;
typedef __attribute__((ext_vector_type(4))) float f32x4;

static __device__ __forceinline__ ushort_t f2bf(float x) {
  union { float f; uint_t u; } v; v.f = x;
  uint_t r = v.u + 0x7fffu + ((v.u >> 16) & 1u);
  return (ushort_t)(r >> 16);
}

// ---------------------------------------------------------------------------
// Projections -> bf16 packed tensors.
// z=0: Qb[b][n][64] = {q proj(32), sqrt(0.1)*xhat(3), zeros(29)}
// z=1: Kb same with k proj
// z=2..5: Vt[b][c][n] channel-major, 32 channels per z
// ---------------------------------------------------------------------------
__global__ __launch_bounds__(256, 4)
void proj2_kernel(const float* __restrict__ x, const float* __restrict__ xyz,
                  const float* __restrict__ Wq, const float* __restrict__ bq,
                  const float* __restrict__ Wk, const float* __restrict__ bk,
                  const float* __restrict__ Wv, const float* __restrict__ bv,
                  ushort_t* __restrict__ Qb, ushort_t* __restrict__ Kb,
                  ushort_t* __restrict__ Vt) {
  __shared__ float wt[128 * 36];  // wt[c*36 + r], r<32
  const int tid = threadIdx.x;
  const int b = blockIdx.y, z = blockIdx.z;
  const int n = blockIdx.x * 256 + tid;

  const float* W; const float* bias; int c0 = 0;
  if (z == 0)      { W = Wq; bias = bq; }
  else if (z == 1) { W = Wk; bias = bk; }
  else { c0 = (z - 2) * 32; W = Wv + (size_t)c0 * 128; bias = bv + c0; }

  for (int idx = tid; idx < 32 * 128; idx += 256) {
    int r = idx >> 7, c = idx & 127;
    wt[c * 36 + r] = W[idx];
  }
  __syncthreads();

  float acc[32];
#pragma unroll
  for (int j = 0; j < 32; ++j) acc[j] = bias[j];

  const float* xb = x + (size_t)b * NCH * NPTS + n;
#pragma unroll 4
  for (int c = 0; c < 128; ++c) {
    float xv = xb[(size_t)c * NPTS];
    const float4* w4 = (const float4*)&wt[c * 36];
#pragma unroll
    for (int j4 = 0; j4 < 8; ++j4) {
      float4 w = w4[j4];
      acc[j4 * 4 + 0] = fmaf(w.x, xv, acc[j4 * 4 + 0]);
      acc[j4 * 4 + 1] = fmaf(w.y, xv, acc[j4 * 4 + 1]);
      acc[j4 * 4 + 2] = fmaf(w.z, xv, acc[j4 * 4 + 2]);
      acc[j4 * 4 + 3] = fmaf(w.w, xv, acc[j4 * 4 + 3]);
    }
  }

  if (z <= 1) {
    ushort_t row[64];
#pragma unroll
    for (int j = 0; j < 32; ++j) row[j] = f2bf(acc[j]);
    float xa = xyz[((size_t)b * NPTS + n) * 3 + 0];
    float xc = xyz[((size_t)b * NPTS + n) * 3 + 1];
    float xd = xyz[((size_t)b * NPTS + n) * 3 + 2];
    float rn = 0.31622776601683794f /
               (sqrtf(xa * xa + xc * xc + xd * xd) + 1e-8f);
    row[32] = f2bf(xa * rn); row[33] = f2bf(xc * rn); row[34] = f2bf(xd * rn);
#pragma unroll
    for (int j = 35; j < 64; ++j) row[j] = 0;
    ushort_t* dst = (z == 0 ? Qb : Kb) + ((size_t)b * NPTS + n) * 64;
#pragma unroll
    for (int j = 0; j < 8; ++j)
      *(bf16x8*)(dst + j * 8) = *(const bf16x8*)(row + j * 8);
  } else {
#pragma unroll
    for (int j = 0; j < 32; ++j)
      Vt[((size_t)b * NCH + c0 + j) * NPTS + n] = f2bf(acc[j]);
  }
}

// ---------------------------------------------------------------------------
// MFMA flash attention. S^T = K * Q^T so softmax state is per-lane (q=lane&15).
// 16 q / wave, 64 q / block, TK=64 keys per tile, key-split over blockIdx.z.
// ---------------------------------------------------------------------------
__global__ __launch_bounds__(256, 4)
void attn_mfma_kernel(const ushort_t* __restrict__ Qb,
                      const ushort_t* __restrict__ Kb,
                      const ushort_t* __restrict__ Vt,
                      float* __restrict__ PACC, float* __restrict__ PM,
                      float* __restrict__ PL) {
  __shared__ ushort_t Klds[64 * 72];    // [key][64 d + 8 pad]
  __shared__ ushort_t Vlds[128 * 72];   // [ch][64 key + 8 pad]
  const int tid = threadIdx.x;
  const int lane = tid & 63, w = tid >> 6;
  const int li = lane & 15, hi = lane >> 4;
  const int qblk = blockIdx.x, b = blockIdx.y, s = blockIdx.z;

  // Q^T B-fragments (persistent): lane holds q = base + li, d = hi*8 + dc*32 + j
  bf16x8 qf0, qf1;
  {
    const int q = qblk * 64 + w * 16 + li;
    const ushort_t* qp = Qb + ((size_t)b * NPTS + q) * 64 + hi * 8;
    qf0 = *(const bf16x8*)(qp);
    qf1 = *(const bf16x8*)(qp + 32);
  }

  f32x4 O[8];
#pragma unroll
  for (int f = 0; f < 8; ++f) O[f] = (f32x4)(0.f);
  float M = -1e30f, l = 0.f;

  const int m00 = s * (NPTS / 2);
  const ushort_t* kgb = Kb + (size_t)b * NPTS * 64;
  const ushort_t* vgb = Vt + (size_t)b * NCH * NPTS;

  // staging maps (constant per thread)
  const int ku0 = tid, ku1 = tid + 256;
  const int kkey0 = ku0 >> 3, kseg0 = ku0 & 7;
  const int kkey1 = ku1 >> 3, kseg1 = ku1 & 7;

  const int src0 = li + (((2 * hi) & 3) << 4);      // transpose src, j<4
  const int src1 = li + (((2 * hi + 1) & 3) << 4);  // transpose src, j>=4
  const bool selB = (hi & 2) != 0;

  for (int t = 0; t < 64; ++t) {
    const int m0 = m00 + t * 64;
    __syncthreads();
    {
      // K tile: 64 keys x 64 d
      bf16x8 k0 = *(const bf16x8*)(kgb + ((size_t)(m0 + kkey0)) * 64 + kseg0 * 8);
      bf16x8 k1 = *(const bf16x8*)(kgb + ((size_t)(m0 + kkey1)) * 64 + kseg1 * 8);
      // V tile: 128 ch x 64 keys
      bf16x8 v0 = *(const bf16x8*)(vgb + (size_t)(ku0 >> 3) * NPTS + m0 + (ku0 & 7) * 8);
      bf16x8 v1 = *(const bf16x8*)(vgb + (size_t)(ku1 >> 3) * NPTS + m0 + (ku1 & 7) * 8);
      bf16x8 v2 = *(const bf16x8*)(vgb + (size_t)((tid + 512) >> 3) * NPTS + m0 + (tid & 7) * 8);
      bf16x8 v3 = *(const bf16x8*)(vgb + (size_t)((tid + 768) >> 3) * NPTS + m0 + (tid & 7) * 8);
      *(bf16x8*)(Klds + kkey0 * 72 + kseg0 * 8) = k0;
      *(bf16x8*)(Klds + kkey1 * 72 + kseg1 * 8) = k1;
      *(bf16x8*)(Vlds + (ku0 >> 3) * 72 + (ku0 & 7) * 8) = v0;
      *(bf16x8*)(Vlds + (ku1 >> 3) * 72 + (ku1 & 7) * 8) = v1;
      *(bf16x8*)(Vlds + ((tid + 512) >> 3) * 72 + (tid & 7) * 8) = v2;
      *(bf16x8*)(Vlds + ((tid + 768) >> 3) * 72 + (tid & 7) * 8) = v3;
    }
    __syncthreads();

    // --- S^T = K * Q^T : 4 key-frags, lane holds (q=li, keys f*16+hi*4+r)
    f32x4 S[4];
#pragma unroll
    for (int f = 0; f < 4; ++f) {
      const ushort_t* kr = Klds + (f * 16 + li) * 72 + hi * 8;
      bf16x8 ka = *(const bf16x8*)(kr);
      bf16x8 kb2 = *(const bf16x8*)(kr + 32);
      f32x4 acc = __builtin_amdgcn_mfma_f32_16x16x32_bf16(ka, qf0, (f32x4)(0.f), 0, 0, 0);
      S[f] = __builtin_amdgcn_mfma_f32_16x16x32_bf16(kb2, qf1, acc, 0, 0, 0);
    }

    // --- online softmax (per lane: q = li; 16 keys here, 64 across hi)
    float tmax = S[0][0];
#pragma unroll
    for (int f = 0; f < 4; ++f) {
      tmax = fmaxf(tmax, S[f][0]); tmax = fmaxf(tmax, S[f][1]);
      tmax = fmaxf(tmax, S[f][2]); tmax = fmaxf(tmax, S[f][3]);
    }
    tmax = fmaxf(tmax, __shfl_xor(tmax, 16));
    tmax = fmaxf(tmax, __shfl_xor(tmax, 32));
    float Mn = fmaxf(M, tmax);
    float alpha = __expf(M - Mn);
    M = Mn;

    uint_t pk[4][2];
    float ts = 0.f;
#pragma unroll
    for (int f = 0; f < 4; ++f) {
      float p0 = __expf(S[f][0] - M);
      float p1 = __expf(S[f][1] - M);
      float p2 = __expf(S[f][2] - M);
      float p3 = __expf(S[f][3] - M);
      ts += (p0 + p1) + (p2 + p3);
      pk[f][0] = (uint_t)f2bf(p0) | ((uint_t)f2bf(p1) << 16);
      pk[f][1] = (uint_t)f2bf(p2) | ((uint_t)f2bf(p3) << 16);
    }
    ts += __shfl_xor(ts, 16);
    ts += __shfl_xor(ts, 32);
    l = l * alpha + ts;

    // rescale O: row r of O is q_local = hi*4 + r -> alpha from lane (hi*4+r)
    {
      f32x4 av;
      av[0] = __shfl(alpha, hi * 4 + 0);
      av[1] = __shfl(alpha, hi * 4 + 1);
      av[2] = __shfl(alpha, hi * 4 + 2);
      av[3] = __shfl(alpha, hi * 4 + 3);
#pragma unroll
      for (int f = 0; f < 8; ++f) O[f] *= av;
    }

    // --- transpose P (C-layout) -> A-fragments, in-register shuffles
#pragma unroll
    for (int kc = 0; kc < 2; ++kc) {
      int aA, aB, a0, a1, a2, a3;
      aA = __shfl((int)pk[2 * kc][0], src0);
      aB = __shfl((int)pk[2 * kc + 1][0], src0);
      a0 = selB ? aB : aA;
      aA = __shfl((int)pk[2 * kc][1], src0);
      aB = __shfl((int)pk[2 * kc + 1][1], src0);
      a1 = selB ? aB : aA;
      aA = __shfl((int)pk[2 * kc][0], src1);
      aB = __shfl((int)pk[2 * kc + 1][0], src1);
      a2 = selB ? aB : aA;
      aA = __shfl((int)pk[2 * kc][1], src1);
      aB = __shfl((int)pk[2 * kc + 1][1], src1);
      a3 = selB ? aB : aA;
      union { int i[4]; bf16x8 v; } au;
      au.i[0] = a0; au.i[1] = a1; au.i[2] = a2; au.i[3] = a3;
      bf16x8 Afrag = au.v;

      // --- O += P * V : B-frag = Vlds[ch=f*16+li][keys kc*32+hi*8..]
#pragma unroll
      for (int f = 0; f < 8; ++f) {
        bf16x8 vf = *(const bf16x8*)(Vlds + (f * 16 + li) * 72 + hi * 8 + kc * 32);
        O[f] = __builtin_amdgcn_mfma_f32_16x16x32_bf16(Afrag, vf, O[f], 0, 0, 0);
      }
    }
  }

  // epilogue: store raw O (native layout), M, l
  {
    size_t base = ((((size_t)(s * NB + b) * 128 + qblk) * 4 + w) * 8) * 64 + lane;
#pragma unroll
    for (int f = 0; f < 8; ++f)
      *(f32x4*)(PACC + (base + (size_t)f * 64) * 4) = O[f];
    if (lane < 16) {
      int n = qblk * 64 + w * 16 + lane;
      PM[(size_t)(s * NB + b) * NPTS + n] = M;
      PL[(size_t)(s * NB + b) * NPTS + n] = l;
    }
  }
}

// ---------------------------------------------------------------------------
// Merge 2 key-splits + gamma + residual, LDS transpose for coalesced output.
// ---------------------------------------------------------------------------
__global__ __launch_bounds__(256, 4)
void merge2_kernel(const float* __restrict__ PACC, const float* __restrict__ PM,
                   const float* __restrict__ PL, const float* __restrict__ x,
                   const float* __restrict__ gamma, float* __restrict__ out) {
  __shared__ float c1s[64], c2s[64];
  __shared__ float ldso[128 * 68];
  const int tid = threadIdx.x;
  const int qblk = blockIdx.x, b = blockIdx.y;
  const int qb = qblk * 64;

  if (tid < 64) {
    int n = qb + tid;
    float M1 = PM[(size_t)b * NPTS + n];
    float M2 = PM[(size_t)(NB + b) * NPTS + n];
    float l1 = PL[(size_t)b * NPTS + n];
    float l2 = PL[(size_t)(NB + b) * NPTS + n];
    float Mm = fmaxf(M1, M2);
    float w1 = __expf(M1 - Mm), w2 = __expf(M2 - Mm);
    float g = gamma[0] / (w1 * l1 + w2 * l2);
    c1s[tid] = w1 * g;
    c2s[tid] = w2 * g;
  }
  __syncthreads();

  const size_t b1 = ((size_t)b * 128 + qblk) * 2048;
  const size_t b2 = ((size_t)(NB + b) * 128 + qblk) * 2048;
#pragma unroll
  for (int j = 0; j < 8; ++j) {
    int u = tid + j * 256;
    f32x4 a1 = *(const f32x4*)(PACC + (b1 + u) * 4);
    f32x4 a2 = *(const f32x4*)(PACC + (b2 + u) * 4);
    int q0 = (u >> 9) * 16 + ((u & 63) >> 4) * 4;
    int ch = ((u >> 6) & 7) * 16 + (u & 15);
    f32x4 r;
#pragma unroll
    for (int rr = 0; rr < 4; ++rr)
      r[rr] = a1[rr] * c1s[q0 + rr] + a2[rr] * c2s[q0 + rr];
    *(f32x4*)&ldso[ch * 68 + q0] = r;
  }
  __syncthreads();

  const float* xb = x + (size_t)b * NCH * NPTS;
  float* ob = out + (size_t)b * NCH * NPTS;
#pragma unroll
  for (int j = 0; j < 8; ++j) {
    int v = (tid + j * 256) * 4;
    int ch = v >> 6, q = v & 63;
    f32x4 tv = *(const f32x4*)&ldso[ch * 68 + q];
    f32x4 xv = *(const f32x4*)(xb + (size_t)ch * NPTS + qb + q);
    tv += xv;
    *(f32x4*)(ob + (size_t)ch * NPTS + qb + q) = tv;
  }
}

// ---------------------------------------------------------------------------
extern "C" void kernel_launch(void* const* d_in, const int* in_sizes, int n_in,
                              void* d_out, int out_size, void* d_ws,
                              size_t ws_size, hipStream_t stream) {
  const float* x     = (const float*)d_in[0];
  const float* xyz   = (const float*)d_in[1];
  const float* Wq    = (const float*)d_in[2];
  const float* bq    = (const float*)d_in[3];
  const float* Wk    = (const float*)d_in[4];
  const float* bk    = (const float*)d_in[5];
  const float* Wv    = (const float*)d_in[6];
  const float* bv    = (const float*)d_in[7];
  const float* gamma = (const float*)d_in[8];
  float* out = (float*)d_out;

  const size_t BN = (size_t)NB * NPTS;
  ushort_t* Qb = (ushort_t*)d_ws;
  ushort_t* Kb = Qb + BN * 64;
  ushort_t* Vt = Kb + BN * 64;
  float* PACC = (float*)(Vt + BN * NCH);
  float* PM = PACC + 2 * BN * NCH;
  float* PL = PM + 2 * BN;

  proj2_kernel<<<dim3(NPTS / 256, NB, 6), 256, 0, stream>>>(
      x, xyz, Wq, bq, Wk, bk, Wv, bv, Qb, Kb, Vt);
  attn_mfma_kernel<<<dim3(NPTS / 64, NB, 2), 256, 0, stream>>>(
      Qb, Kb, Vt, PACC, PM, PL);
  merge2_kernel<<<dim3(NPTS / 64, NB), 256, 0, stream>>>(PACC, PM, PL, x,
                                                         gamma, out);
  (void)in_sizes; (void)n_in; (void)out_size; (void)ws_size;
}

// Round 3
// 295.523 us; speedup vs baseline: 6.1070x; 1.1097x over previous
//
#include <hip/hip_runtime.h>

#define NPTS 8192
#define NB 4
#define NCH 128
#define DQK 48
#define TK 64
#define SPLIT 4
#define KEYS_PER (NPTS / SPLIT)   // 2048
#define ROUNDS (KEYS_PER / TK)    // 32

typedef unsigned short ushort_t;
typedef unsigned int uint_t;
typedef __attribute__((ext_vector_type(8))) short bf16x8;
typedef __attribute__((ext_vector_type(4))) float f32x4;
typedef __attribute__((ext_vector_type(16))) float f32x16;

static __device__ __forceinline__ ushort_t f2bf(float x) {
  union { float f; uint_t u; } v; v.f = x;
  uint_t r = v.u + 0x7fffu + ((v.u >> 16) & 1u);
  return (ushort_t)(r >> 16);
}
static __device__ __forceinline__ float bf2f(ushort_t u) {
  union { uint_t i; float f; } v; v.i = ((uint_t)u) << 16; return v.f;
}

typedef __attribute__((address_space(1))) void void_g;
typedef __attribute__((address_space(3))) void void_l;
static __device__ __forceinline__ void gload_lds16(const ushort_t* g, ushort_t* l) {
  __builtin_amdgcn_global_load_lds((void_g*)(ushort_t*)g, (void_l*)l, 16, 0, 0);
}

// ---------------------------------------------------------------------------
// Projections. z=0: Q&K rows [n][48] = {proj(32), sqrt(0.1)*xhat(3), 0...};
// z=1: V ch 0..63, z=2: V ch 64..127 -> Vt[b][ch][n] bf16.
// Weights read via uniform (scalar) loads - no LDS.
// ---------------------------------------------------------------------------
__global__ __launch_bounds__(256, 2)
void proj3_kernel(const float* __restrict__ x, const float* __restrict__ xyz,
                  const float* __restrict__ Wq, const float* __restrict__ bq,
                  const float* __restrict__ Wk, const float* __restrict__ bk,
                  const float* __restrict__ Wv, const float* __restrict__ bv,
                  ushort_t* __restrict__ Qb, ushort_t* __restrict__ Kb,
                  ushort_t* __restrict__ Vt) {
  const int tid = threadIdx.x;
  const int b = blockIdx.y, z = blockIdx.z;
  const int n = blockIdx.x * 256 + tid;
  const int c0 = (z == 0) ? 0 : (z - 1) * 64;

  const float* W0 = (z == 0) ? Wq : (Wv + (size_t)c0 * 128);
  const float* W1 = (z == 0) ? Wk : (Wv + (size_t)(c0 + 32) * 128);
  const float* b0 = (z == 0) ? bq : (bv + c0);
  const float* b1 = (z == 0) ? bk : (bv + c0 + 32);

  float acc[64];
#pragma unroll
  for (int j = 0; j < 32; ++j) { acc[j] = b0[j]; acc[32 + j] = b1[j]; }

  const float* xb = x + (size_t)b * NCH * NPTS + n;
#pragma unroll 2
  for (int c = 0; c < 128; ++c) {
    float xv = xb[(size_t)c * NPTS];
#pragma unroll
    for (int j = 0; j < 32; ++j) {
      acc[j]      = fmaf(W0[j * 128 + c], xv, acc[j]);
      acc[32 + j] = fmaf(W1[j * 128 + c], xv, acc[32 + j]);
    }
  }

  if (z == 0) {
    float xa = xyz[((size_t)b * NPTS + n) * 3 + 0];
    float xc = xyz[((size_t)b * NPTS + n) * 3 + 1];
    float xd = xyz[((size_t)b * NPTS + n) * 3 + 2];
    float rn = 0.31622776601683794f / (sqrtf(xa * xa + xc * xc + xd * xd) + 1e-8f);
    ushort_t hx = f2bf(xa * rn), hy = f2bf(xc * rn), hz = f2bf(xd * rn);

    ushort_t row[48];
#pragma unroll
    for (int j = 0; j < 32; ++j) row[j] = f2bf(acc[j]);
    row[32] = hx; row[33] = hy; row[34] = hz;
#pragma unroll
    for (int j = 35; j < 48; ++j) row[j] = 0;
    ushort_t* dq = Qb + ((size_t)b * NPTS + n) * DQK;
#pragma unroll
    for (int j = 0; j < 6; ++j) *(bf16x8*)(dq + j * 8) = *(const bf16x8*)(row + j * 8);

#pragma unroll
    for (int j = 0; j < 32; ++j) row[j] = f2bf(acc[32 + j]);
    ushort_t* dk = Kb + ((size_t)b * NPTS + n) * DQK;
#pragma unroll
    for (int j = 0; j < 6; ++j) *(bf16x8*)(dk + j * 8) = *(const bf16x8*)(row + j * 8);
  } else {
#pragma unroll
    for (int j = 0; j < 64; ++j)
      Vt[((size_t)b * NCH + c0 + j) * NPTS + n] = f2bf(acc[j]);
  }
}

// ---------------------------------------------------------------------------
// MFMA flash attention, 32x32x16, 64 q/wave, 256 q/block, TK=64 keys/tile.
// Constant-shift softmax (no running max). Fragment-major LDS staged by
// global_load_lds width=16. Key-split over 4 segments (merged later).
// ---------------------------------------------------------------------------
__global__ __launch_bounds__(256, 2)
void attn32_kernel(const ushort_t* __restrict__ Qb, const ushort_t* __restrict__ Kb,
                   const ushort_t* __restrict__ Vt,
                   ushort_t* __restrict__ PACC, float* __restrict__ PL) {
  // 22 frags: K = kb*3+c (6), V = 6 + f*4 + kk (16); each 64 lanes x 16B
  __shared__ __align__(16) ushort_t L[22 * 512];
  const int tid = threadIdx.x;
  const int lane = tid & 63, w = tid >> 6;
  const int l31 = lane & 31, h = lane >> 5;

  // XCD-locality swizzle: xcd = lin&7 sees only 2 (b,seg) combos
  const int lin = blockIdx.x;
  const int bs = (lin & 7) | ((lin >> 8) << 3);   // 0..15: b = bs&3, seg = bs>>2
  const int b = bs & 3, sseg = bs >> 2;
  const int qblk = (lin >> 3) & 31;
  const int q0w = qblk * 256 + w * 64;
  const int m00 = sseg * KEYS_PER;

  // persistent Q^T B-frags: q = q0w + g*32 + l31, d = c*16 + h*8 + j
  bf16x8 qf[2][3];
#pragma unroll
  for (int g = 0; g < 2; ++g)
#pragma unroll
    for (int c = 0; c < 3; ++c)
      qf[g][c] = *(const bf16x8*)(Qb + ((size_t)b * NPTS + q0w + g * 32 + l31) * DQK +
                                  c * 16 + h * 8);

  // staging pointer setup: wave w handles frags {w, w+4, ...}
  const ushort_t* gp[6];
  int fids[6], adv[6];
  const int nf = (w < 2) ? 6 : 5;
  for (int i = 0; i < nf; ++i) {
    int fi = w + 4 * i;
    fids[i] = fi;
    if (fi < 6) {
      int kb = fi / 3, c = fi - kb * 3;
      gp[i] = Kb + ((size_t)b * NPTS + m00 + kb * 32 + l31) * DQK + c * 16 + h * 8;
      adv[i] = TK * DQK;
    } else {
      int vi = fi - 6, f = vi >> 2, kk = vi & 3;
      gp[i] = Vt + ((size_t)b * NCH + f * 32 + l31) * NPTS + m00 + kk * 16 + h * 8;
      adv[i] = TK;
    }
  }

  f32x16 O[2][4];
#pragma unroll
  for (int g = 0; g < 2; ++g)
#pragma unroll
    for (int f = 0; f < 4; ++f) O[g][f] = (f32x16)(0.f);
  float lsum0 = 0.f, lsum1 = 0.f;

#pragma unroll 1
  for (int t = 0; t < ROUNDS; ++t) {
    __syncthreads();  // everyone done reading L from previous round
    for (int i = 0; i < nf; ++i) {
      gload_lds16(gp[i], &L[fids[i] * 512]);
      gp[i] += adv[i];
    }
    __syncthreads();  // drain DMA (compiler emits vmcnt(0)) + publish

#pragma unroll
    for (int kb = 0; kb < 2; ++kb) {
      bf16x8 kf0 = *(const bf16x8*)(L + (kb * 3 + 0) * 512 + lane * 8);
      bf16x8 kf1 = *(const bf16x8*)(L + (kb * 3 + 1) * 512 + lane * 8);
      bf16x8 kf2 = *(const bf16x8*)(L + (kb * 3 + 2) * 512 + lane * 8);

      uint_t pk[2][8];
#pragma unroll
      for (int g = 0; g < 2; ++g) {
        f32x16 S = __builtin_amdgcn_mfma_f32_32x32x16_bf16(kf0, qf[g][0], (f32x16)(0.f), 0, 0, 0);
        S = __builtin_amdgcn_mfma_f32_32x32x16_bf16(kf1, qf[g][1], S, 0, 0, 0);
        S = __builtin_amdgcn_mfma_f32_32x32x16_bf16(kf2, qf[g][2], S, 0, 0, 0);
        // constant-shift softmax: p = exp(s - 20); data-bounded, no overflow
        float p[16];
        float ts = 0.f;
#pragma unroll
        for (int r = 0; r < 16; ++r) { p[r] = __expf(S[r] - 20.0f); ts += p[r]; }
        if (g == 0) lsum0 += ts; else lsum1 += ts;
#pragma unroll
        for (int i = 0; i < 8; ++i)
          pk[g][i] = __builtin_amdgcn_perm(__float_as_uint(p[2 * i + 1]),
                                           __float_as_uint(p[2 * i]), 0x07060302u);
      }

      // cross-half exchange: X = partner-half's pk
      uint_t X[2][8];
#pragma unroll
      for (int g = 0; g < 2; ++g)
#pragma unroll
        for (int i = 0; i < 8; ++i) X[g][i] = (uint_t)__shfl_xor((int)pk[g][i], 32);

#pragma unroll
      for (int kkl = 0; kkl < 2; ++kkl) {
        bf16x8 A[2];
#pragma unroll
        for (int g = 0; g < 2; ++g) {
          union { uint_t u[4]; bf16x8 v; } au;
          au.u[0] = h ? X[g][4 * kkl + 2] : pk[g][4 * kkl + 0];
          au.u[1] = h ? X[g][4 * kkl + 3] : pk[g][4 * kkl + 1];
          au.u[2] = h ? pk[g][4 * kkl + 2] : X[g][4 * kkl + 0];
          au.u[3] = h ? pk[g][4 * kkl + 3] : X[g][4 * kkl + 1];
          A[g] = au.v;
        }
#pragma unroll
        for (int f = 0; f < 4; ++f) {
          bf16x8 vf = *(const bf16x8*)(L + (6 + f * 4 + kb * 2 + kkl) * 512 + lane * 8);
          O[0][f] = __builtin_amdgcn_mfma_f32_32x32x16_bf16(A[0], vf, O[0][f], 0, 0, 0);
          O[1][f] = __builtin_amdgcn_mfma_f32_32x32x16_bf16(A[1], vf, O[1][f], 0, 0, 0);
        }
      }
    }
  }

  // epilogue: reduce l across halves, store raw O (bf16) + l
  lsum0 += __shfl_xor(lsum0, 32);
  lsum1 += __shfl_xor(lsum1, 32);
  const size_t pbase = (((size_t)bs * 32 + qblk) * 4 + w) * 2;
#pragma unroll
  for (int g = 0; g < 2; ++g) {
#pragma unroll
    for (int f = 0; f < 4; ++f) {
      union { ushort_t u[16]; bf16x8 v[2]; } pu;
#pragma unroll
      for (int r = 0; r < 16; ++r) pu.u[r] = f2bf(O[g][f][r]);
      size_t idx = ((pbase + g) * 4 + f) * 1024 + (size_t)lane * 16;
      *(bf16x8*)(PACC + idx) = pu.v[0];
      *(bf16x8*)(PACC + idx + 8) = pu.v[1];
    }
    if (lane < 32)
      PL[(size_t)bs * NPTS + q0w + g * 32 + lane] = (g == 0) ? lsum0 : lsum1;
  }
}

// ---------------------------------------------------------------------------
// Merge 4 key-split partials (linear: constant-shift softmax) + gamma + x.
// grid (qblk 32, b 4, f 4)
// ---------------------------------------------------------------------------
__global__ __launch_bounds__(256, 4)
void merge4_kernel(const ushort_t* __restrict__ PACC, const float* __restrict__ PL,
                   const float* __restrict__ x, const float* __restrict__ gamma,
                   float* __restrict__ out) {
  __shared__ float Linv[256];
  const int tid = threadIdx.x;
  const int qblk = blockIdx.x, b = blockIdx.y, f = blockIdx.z;
  const int q0 = qblk * 256;

  float Ls = 0.f;
#pragma unroll
  for (int s = 0; s < 4; ++s)
    Ls += PL[(size_t)(s * 4 + b) * NPTS + q0 + tid];
  Linv[tid] = gamma[0] / Ls;
  __syncthreads();

  const int ww = tid >> 6, lane = tid & 63, l31 = lane & 31, h = lane >> 5;
  const int ch = f * 32 + l31;
  const float* xrow = x + ((size_t)b * NCH + ch) * NPTS + q0;
  float* orow = out + ((size_t)b * NCH + ch) * NPTS + q0;

#pragma unroll
  for (int g = 0; g < 2; ++g) {
    float acc[16];
#pragma unroll
    for (int r = 0; r < 16; ++r) acc[r] = 0.f;
#pragma unroll
    for (int s = 0; s < 4; ++s) {
      size_t idx = (((((size_t)(s * 4 + b) * 32 + qblk) * 4 + ww) * 2 + g) * 4 + f) * 1024 +
                   (size_t)lane * 16;
      bf16x8 a0 = *(const bf16x8*)(PACC + idx);
      bf16x8 a1 = *(const bf16x8*)(PACC + idx + 8);
#pragma unroll
      for (int r = 0; r < 8; ++r) {
        acc[r] += bf2f((ushort_t)a0[r]);
        acc[8 + r] += bf2f((ushort_t)a1[r]);
      }
    }
    const int qb = ww * 64 + g * 32;
#pragma unroll
    for (int rr = 0; rr < 4; ++rr) {
      int q = qb + 8 * rr + 4 * h;
      f32x4 xv = *(const f32x4*)(xrow + q);
      f32x4 o;
#pragma unroll
      for (int i = 0; i < 4; ++i) o[i] = acc[rr * 4 + i] * Linv[q + i] + xv[i];
      *(f32x4*)(orow + q) = o;
    }
  }
}

// ---------------------------------------------------------------------------
extern "C" void kernel_launch(void* const* d_in, const int* in_sizes, int n_in,
                              void* d_out, int out_size, void* d_ws,
                              size_t ws_size, hipStream_t stream) {
  const float* x     = (const float*)d_in[0];
  const float* xyz   = (const float*)d_in[1];
  const float* Wq    = (const float*)d_in[2];
  const float* bq    = (const float*)d_in[3];
  const float* Wk    = (const float*)d_in[4];
  const float* bk    = (const float*)d_in[5];
  const float* Wv    = (const float*)d_in[6];
  const float* bv    = (const float*)d_in[7];
  const float* gamma = (const float*)d_in[8];
  float* out = (float*)d_out;

  const size_t BN = (size_t)NB * NPTS;
  ushort_t* Qb = (ushort_t*)d_ws;
  ushort_t* Kb = Qb + BN * DQK;
  ushort_t* Vt = Kb + BN * DQK;
  ushort_t* PACC = Vt + BN * NCH;                       // 16*32*4*2*4*1024 bf16
  float* PL = (float*)(PACC + (size_t)16 * 32 * 4 * 2 * 4 * 1024);

  proj3_kernel<<<dim3(NPTS / 256, NB, 3), 256, 0, stream>>>(
      x, xyz, Wq, bq, Wk, bk, Wv, bv, Qb, Kb, Vt);
  attn32_kernel<<<512, 256, 0, stream>>>(Qb, Kb, Vt, PACC, PL);
  merge4_kernel<<<dim3(32, NB, 4), 256, 0, stream>>>(PACC, PL, x, gamma, out);
  (void)in_sizes; (void)n_in; (void)out_size; (void)ws_size;
}

// Round 5
// 239.965 us; speedup vs baseline: 7.5210x; 1.2315x over previous
//
#include <hip/hip_runtime.h>

#define NPTS 8192
#define NB 4
#define NCH 128
#define DQK 48
#define TK 64
#define SPLIT 4
#define KEYS_PER (NPTS / SPLIT)   // 2048
#define ROUNDS (KEYS_PER / TK)    // 32
#define SH2 28.853901f            // 20 * log2(e)
#define LOG2E 1.4426950408889634f

typedef unsigned short ushort_t;
typedef unsigned int uint_t;
typedef __attribute__((ext_vector_type(8))) short bf16x8;
typedef __attribute__((ext_vector_type(4))) float f32x4;
typedef __attribute__((ext_vector_type(16))) float f32x16;

static __device__ __forceinline__ ushort_t f2bf(float x) {
  union { float f; uint_t u; } v; v.f = x;
  uint_t r = v.u + 0x7fffu + ((v.u >> 16) & 1u);
  return (ushort_t)(r >> 16);
}
static __device__ __forceinline__ float bf2f(ushort_t u) {
  union { uint_t i; float f; } v; v.i = ((uint_t)u) << 16; return v.f;
}

typedef __attribute__((address_space(1))) void void_g;
typedef __attribute__((address_space(3))) void void_l;
static __device__ __forceinline__ void gload_lds16(const ushort_t* g, ushort_t* l) {
  __builtin_amdgcn_global_load_lds((void_g*)(ushort_t*)g, (void_l*)l, 16, 0, 0);
}

// ---------------------------------------------------------------------------
// Projections (LDS-staged weights). z=0: Q rows [n][48] scaled by
// log2(e) = {q*log2e (32), sqrt(.1)*log2e*xhat (3), 0...}; z=1: K rows
// (unscaled); z=2..5: V 32-ch chunks -> Vt[b][ch][n] bf16.
// ---------------------------------------------------------------------------
__global__ __launch_bounds__(256, 4)
void proj4_kernel(const float* __restrict__ x, const float* __restrict__ xyz,
                  const float* __restrict__ Wq, const float* __restrict__ bq,
                  const float* __restrict__ Wk, const float* __restrict__ bk,
                  const float* __restrict__ Wv, const float* __restrict__ bv,
                  ushort_t* __restrict__ Qb, ushort_t* __restrict__ Kb,
                  ushort_t* __restrict__ Vt) {
  __shared__ float wt[128 * 36];  // wt[c*36 + r], r<32 (broadcast reads)
  const int tid = threadIdx.x;
  const int b = blockIdx.y, z = blockIdx.z;
  const int n = blockIdx.x * 256 + tid;

  const float* W; const float* bias; int c0 = 0;
  if (z == 0)      { W = Wq; bias = bq; }
  else if (z == 1) { W = Wk; bias = bk; }
  else { c0 = (z - 2) * 32; W = Wv + (size_t)c0 * 128; bias = bv + c0; }

  for (int idx = tid; idx < 32 * 128; idx += 256) {
    int r = idx >> 7, c = idx & 127;
    wt[c * 36 + r] = W[idx];
  }
  __syncthreads();

  float acc[32];
#pragma unroll
  for (int j = 0; j < 32; ++j) acc[j] = bias[j];

  const float* xb = x + (size_t)b * NCH * NPTS + n;
#pragma unroll 4
  for (int c = 0; c < 128; ++c) {
    float xv = xb[(size_t)c * NPTS];
    const float4* w4 = (const float4*)&wt[c * 36];
#pragma unroll
    for (int j4 = 0; j4 < 8; ++j4) {
      float4 w = w4[j4];
      acc[j4 * 4 + 0] = fmaf(w.x, xv, acc[j4 * 4 + 0]);
      acc[j4 * 4 + 1] = fmaf(w.y, xv, acc[j4 * 4 + 1]);
      acc[j4 * 4 + 2] = fmaf(w.z, xv, acc[j4 * 4 + 2]);
      acc[j4 * 4 + 3] = fmaf(w.w, xv, acc[j4 * 4 + 3]);
    }
  }

  if (z <= 1) {
    const float sc = (z == 0) ? LOG2E : 1.0f;
    float xa = xyz[((size_t)b * NPTS + n) * 3 + 0];
    float xc = xyz[((size_t)b * NPTS + n) * 3 + 1];
    float xd = xyz[((size_t)b * NPTS + n) * 3 + 2];
    float rn = 0.31622776601683794f * sc /
               (sqrtf(xa * xa + xc * xc + xd * xd) + 1e-8f);
    ushort_t row[48];
#pragma unroll
    for (int j = 0; j < 32; ++j) row[j] = f2bf(acc[j] * sc);
    row[32] = f2bf(xa * rn); row[33] = f2bf(xc * rn); row[34] = f2bf(xd * rn);
#pragma unroll
    for (int j = 35; j < 48; ++j) row[j] = 0;
    ushort_t* dst = (z == 0 ? Qb : Kb) + ((size_t)b * NPTS + n) * DQK;
#pragma unroll
    for (int j = 0; j < 6; ++j)
      *(bf16x8*)(dst + j * 8) = *(const bf16x8*)(row + j * 8);
  } else {
#pragma unroll
    for (int j = 0; j < 32; ++j)
      Vt[((size_t)b * NCH + c0 + j) * NPTS + n] = f2bf(acc[j]);
  }
}

// ---------------------------------------------------------------------------
// MFMA flash attention, 32x32x16, 64 q/wave, 8 waves = 512 q/block.
// Double-buffered global_load_lds staging, ONE barrier per round.
// exp2-domain constant-shift softmax (Q pre-scaled by log2e).
// ---------------------------------------------------------------------------
__global__ __launch_bounds__(512, 2)
void attn32_kernel(const ushort_t* __restrict__ Qb, const ushort_t* __restrict__ Kb,
                   const ushort_t* __restrict__ Vt,
                   ushort_t* __restrict__ PACC, float* __restrict__ PL) {
  // frag f: K = kb*3+c (6), V = 6 + fch*4 + kk (16); each 64 lanes x 16B
  __shared__ __align__(16) ushort_t L[2][22][512];
  const int tid = threadIdx.x;
  const int lane = tid & 63, w = tid >> 6;
  const int l31 = lane & 31, h = lane >> 5;

  const int lin = blockIdx.x;
  const int bs = lin & 15;          // XCD x sees bs in {x, x+8}: 2 (b,seg) combos
  const int b = bs & 3, sseg = bs >> 2;
  const int qblk = lin >> 4;        // 0..15
  const int q0w = qblk * 512 + w * 64;
  const int m00 = sseg * KEYS_PER;

  // persistent Q^T B-frags: q = q0w + g*32 + l31, d = c*16 + h*8 + j
  bf16x8 qf[2][3];
#pragma unroll
  for (int g = 0; g < 2; ++g)
#pragma unroll
    for (int c = 0; c < 3; ++c)
      qf[g][c] = *(const bf16x8*)(Qb + ((size_t)b * NPTS + q0w + g * 32 + l31) * DQK +
                                  c * 16 + h * 8);

  // staging: wave w handles frags {w, w+8, w+16} (22 total)
  const ushort_t* gp[3];
  int fid[3], adv[3];
  const int nf = (w < 6) ? 3 : 2;
  for (int i = 0; i < nf; ++i) {
    int fi = w + 8 * i;
    fid[i] = fi;
    if (fi < 6) {
      int kb = fi / 3, c = fi - kb * 3;
      gp[i] = Kb + ((size_t)b * NPTS + m00 + kb * 32 + l31) * DQK + c * 16 + h * 8;
      adv[i] = TK * DQK;
    } else {
      int vi = fi - 6, fch = vi >> 2, kk = vi & 3;
      gp[i] = Vt + ((size_t)b * NCH + fch * 32 + l31) * NPTS + m00 + kk * 16 + h * 8;
      adv[i] = TK;
    }
  }

  f32x16 O[2][4];
#pragma unroll
  for (int g = 0; g < 2; ++g)
#pragma unroll
    for (int f = 0; f < 4; ++f) O[g][f] = (f32x16)(0.f);
  float lsum0 = 0.f, lsum1 = 0.f;

  // prologue: stage round 0 into buffer 0
  for (int i = 0; i < nf; ++i) gload_lds16(gp[i], &L[0][fid[i]][0]);

#pragma unroll 1
  for (int t = 0; t < ROUNDS; ++t) {
    __syncthreads();  // auto vmcnt(0): my buf[t&1] DMA drained; all waves synced
    const int cur = t & 1;
    if (t + 1 < ROUNDS) {
      for (int i = 0; i < nf; ++i) {
        gp[i] += adv[i];
        gload_lds16(gp[i], &L[cur ^ 1][fid[i]][0]);  // overlaps with compute below
      }
    }

#pragma unroll
    for (int kb = 0; kb < 2; ++kb) {
      bf16x8 kf0 = *(const bf16x8*)(&L[cur][kb * 3 + 0][0] + lane * 8);
      bf16x8 kf1 = *(const bf16x8*)(&L[cur][kb * 3 + 1][0] + lane * 8);
      bf16x8 kf2 = *(const bf16x8*)(&L[cur][kb * 3 + 2][0] + lane * 8);

      uint_t pk[2][8];
#pragma unroll
      for (int g = 0; g < 2; ++g) {
        f32x16 S = __builtin_amdgcn_mfma_f32_32x32x16_bf16(kf0, qf[g][0], (f32x16)(0.f), 0, 0, 0);
        S = __builtin_amdgcn_mfma_f32_32x32x16_bf16(kf1, qf[g][1], S, 0, 0, 0);
        S = __builtin_amdgcn_mfma_f32_32x32x16_bf16(kf2, qf[g][2], S, 0, 0, 0);
        float p[16];
        float ts = 0.f;
#pragma unroll
        for (int r = 0; r < 16; ++r) {
          p[r] = __builtin_amdgcn_exp2f(S[r] - SH2);
          ts += p[r];
        }
        if (g == 0) lsum0 += ts; else lsum1 += ts;
#pragma unroll
        for (int i = 0; i < 8; ++i)
          pk[g][i] = __builtin_amdgcn_perm(__float_as_uint(p[2 * i + 1]),
                                           __float_as_uint(p[2 * i]), 0x07060302u);
      }

      // cross-half exchange for C->A transpose
      uint_t X[2][8];
#pragma unroll
      for (int g = 0; g < 2; ++g)
#pragma unroll
        for (int i = 0; i < 8; ++i) X[g][i] = (uint_t)__shfl_xor((int)pk[g][i], 32);

#pragma unroll
      for (int kkl = 0; kkl < 2; ++kkl) {
        bf16x8 A[2];
#pragma unroll
        for (int g = 0; g < 2; ++g) {
          union { uint_t u[4]; bf16x8 v; } au;
          au.u[0] = h ? X[g][4 * kkl + 2] : pk[g][4 * kkl + 0];
          au.u[1] = h ? X[g][4 * kkl + 3] : pk[g][4 * kkl + 1];
          au.u[2] = h ? pk[g][4 * kkl + 2] : X[g][4 * kkl + 0];
          au.u[3] = h ? pk[g][4 * kkl + 3] : X[g][4 * kkl + 1];
          A[g] = au.v;
        }
#pragma unroll
        for (int f = 0; f < 4; ++f) {
          bf16x8 vf = *(const bf16x8*)(&L[cur][6 + f * 4 + kb * 2 + kkl][0] + lane * 8);
          O[0][f] = __builtin_amdgcn_mfma_f32_32x32x16_bf16(A[0], vf, O[0][f], 0, 0, 0);
          O[1][f] = __builtin_amdgcn_mfma_f32_32x32x16_bf16(A[1], vf, O[1][f], 0, 0, 0);
        }
      }
    }
  }

  // epilogue
  lsum0 += __shfl_xor(lsum0, 32);
  lsum1 += __shfl_xor(lsum1, 32);
  const size_t pbase = (((size_t)bs * 16 + qblk) * 8 + w) * 2;
#pragma unroll
  for (int g = 0; g < 2; ++g) {
#pragma unroll
    for (int f = 0; f < 4; ++f) {
      union { ushort_t u[16]; bf16x8 v[2]; } pu;
#pragma unroll
      for (int r = 0; r < 16; ++r) pu.u[r] = f2bf(O[g][f][r]);
      size_t idx = ((pbase + g) * 4 + f) * 1024 + (size_t)lane * 16;
      *(bf16x8*)(PACC + idx) = pu.v[0];
      *(bf16x8*)(PACC + idx + 8) = pu.v[1];
    }
    if (lane < 32)
      PL[(size_t)bs * NPTS + q0w + g * 32 + lane] = (g == 0) ? lsum0 : lsum1;
  }
}

// ---------------------------------------------------------------------------
// Merge 4 key-split partials (linear: constant-shift softmax) + gamma + x.
// grid (qblk2 32, b 4, f 4); each block: 256 q x 32 ch.
// ---------------------------------------------------------------------------
__global__ __launch_bounds__(256, 4)
void merge4_kernel(const ushort_t* __restrict__ PACC, const float* __restrict__ PL,
                   const float* __restrict__ x, const float* __restrict__ gamma,
                   float* __restrict__ out) {
  __shared__ float Linv[256];
  const int tid = threadIdx.x;
  const int qblk2 = blockIdx.x, b = blockIdx.y, f = blockIdx.z;
  const int q0 = qblk2 * 256;

  float Ls = 0.f;
#pragma unroll
  for (int s = 0; s < 4; ++s)
    Ls += PL[(size_t)(s * 4 + b) * NPTS + q0 + tid];
  Linv[tid] = gamma[0] / Ls;
  __syncthreads();

  const int ww = tid >> 6, lane = tid & 63, l31 = lane & 31, h = lane >> 5;
  const int ch = f * 32 + l31;
  const float* xrow = x + ((size_t)b * NCH + ch) * NPTS + q0;
  float* orow = out + ((size_t)b * NCH + ch) * NPTS + q0;

#pragma unroll
  for (int g = 0; g < 2; ++g) {
    float acc[16];
#pragma unroll
    for (int r = 0; r < 16; ++r) acc[r] = 0.f;
#pragma unroll
    for (int s = 0; s < 4; ++s) {
      size_t idx = (((((size_t)(s * 4 + b) * 16 + (qblk2 >> 1)) * 8 +
                      (qblk2 & 1) * 4 + ww) * 2 + g) * 4 + f) * 1024 +
                   (size_t)lane * 16;
      bf16x8 a0 = *(const bf16x8*)(PACC + idx);
      bf16x8 a1 = *(const bf16x8*)(PACC + idx + 8);
#pragma unroll
      for (int r = 0; r < 8; ++r) {
        acc[r] += bf2f((ushort_t)a0[r]);
        acc[8 + r] += bf2f((ushort_t)a1[r]);
      }
    }
    const int qb = ww * 64 + g * 32;
#pragma unroll
    for (int rr = 0; rr < 4; ++rr) {
      int q = qb + 8 * rr + 4 * h;
      f32x4 xv = *(const f32x4*)(xrow + q);
      f32x4 o;
#pragma unroll
      for (int i = 0; i < 4; ++i) o[i] = acc[rr * 4 + i] * Linv[q + i] + xv[i];
      *(f32x4*)(orow + q) = o;
    }
  }
}

// ---------------------------------------------------------------------------
extern "C" void kernel_launch(void* const* d_in, const int* in_sizes, int n_in,
                              void* d_out, int out_size, void* d_ws,
                              size_t ws_size, hipStream_t stream) {
  const float* x     = (const float*)d_in[0];
  const float* xyz   = (const float*)d_in[1];
  const float* Wq    = (const float*)d_in[2];
  const float* bq    = (const float*)d_in[3];
  const float* Wk    = (const float*)d_in[4];
  const float* bk    = (const float*)d_in[5];
  const float* Wv    = (const float*)d_in[6];
  const float* bv    = (const float*)d_in[7];
  const float* gamma = (const float*)d_in[8];
  float* out = (float*)d_out;

  const size_t BN = (size_t)NB * NPTS;
  ushort_t* Qb = (ushort_t*)d_ws;
  ushort_t* Kb = Qb + BN * DQK;
  ushort_t* Vt = Kb + BN * DQK;
  ushort_t* PACC = Vt + BN * NCH;   // 16 bs * 16 qblk * 8 w * 2 g * 4 f * 1024
  float* PL = (float*)(PACC + (size_t)16 * 16 * 8 * 2 * 4 * 1024);

  proj4_kernel<<<dim3(NPTS / 256, NB, 6), 256, 0, stream>>>(
      x, xyz, Wq, bq, Wk, bk, Wv, bv, Qb, Kb, Vt);
  attn32_kernel<<<256, 512, 0, stream>>>(Qb, Kb, Vt, PACC, PL);
  merge4_kernel<<<dim3(32, NB, 4), 256, 0, stream>>>(PACC, PL, x, gamma, out);
  (void)in_sizes; (void)n_in; (void)out_size; (void)ws_size;
}